// Round 10
// baseline (346.792 us; speedup 1.0000x reference)
//
#include <hip/hip_runtime.h>

// ---- problem constants ----
// B=16, N=512, D_MODEL=256, NUM_RBF=50, CUTOFF=12
// delta = 12/49, width = 2*delta
// S = 2.45229158;  D = delta*S = sqrt(log2 e)/2 = 0.60056098
// Key identity: 4*D^2 = log2(e)  =>  2^{-m^2*D^2} = e^{-m^2/4}
//
// R9 core: per pair only taps k = k* + m, m in [-7, +8], matter
// (|dropped| < 8e-7). With u0 = dS - k*'D (|u0| <= D/2):
//   g_{k*+m} = 2^{-(u0 - mD)^2} = t0 * Ap^m * e^{-m^2/4}
//   t0 = 2^{-u0^2},  Ap = 2^{2D*u0} in [0.78, 1.29]
// Scatter-accumulate into a per-wave LDS histogram (ds_add_f32), 4 bank-
// staggered replicas (stride 97) keyed by lane&3 to cut same-address and
// same-bank serialization.
#define S_C    2.45229158f
#define D_C    0.60056098f
#define INVD_C 1.66510998f   /* 1/D */
#define TWO_DS 1.20112196f   /* 2*D */

// e^{-m^2/4}, m = 1..8
#define E1f 0.778800783f
#define E2f 0.367879441f
#define E3f 0.105399225f
#define E4f 1.83156389e-2f
#define E5f 1.93045414e-3f
#define E6f 1.23409804e-4f
#define E7f 4.78511739e-6f
#define E8f 1.12535175e-7f

__device__ __forceinline__ float fast_exp2(float x) {
#if __has_builtin(__builtin_amdgcn_exp2f)
    return __builtin_amdgcn_exp2f(x);
#else
    float r;
    asm("v_exp_f32 %0, %1" : "=v"(r) : "v"(x));
    return r;
#endif
}
__device__ __forceinline__ float fast_sqrt(float x) {
#if __has_builtin(__builtin_amdgcn_sqrtf)
    return __builtin_amdgcn_sqrtf(x);
#else
    return sqrtf(x);
#endif
}

// 15/16-tap windowed RBF scatter for the 512 neighbors of row (b,i).
// hw = this wave's 4x97 histogram block (zeroed). Writes indices [1,86].
__device__ __forceinline__ void rbf_hist_core(const float* __restrict__ posb,
                                              int lane, float pix, float piy,
                                              float piz, float* __restrict__ hw)
{
    float* hrep = hw + (lane & 3) * 97;   // replica for this lane

#pragma unroll 2
    for (int jj = 0; jj < 8; ++jj) {
        const float* pj = posb + jj * 192 + lane * 3;
        const float dx = pix - pj[0];
        const float dy = piy - pj[1];
        const float dz = piz - pj[2];
        const float d2 = fmaf(dx, dx, fmaf(dy, dy, fmaf(dz, dz, 1e-8f)));
        float dS = fminf(fast_sqrt(d2) * S_C, 42.0f);  // g==0 beyond for all k

        const float kf = rintf(dS * INVD_C);           // k* in [0, 70]
        const int   ki = (int)kf;
        const float u0 = fmaf(-kf, D_C, dS);           // |u0| <= D/2
        const float Ap = fast_exp2(u0 * TWO_DS);
        const float An = fast_exp2(u0 * -TWO_DS);      // Ap^-1, exact
        const float t0 = fast_exp2(-(u0 * u0));

        float* hp = hrep + (8 + ki);                    // taps span [1, 86]
        float cp = t0, cn = t0;
        unsafeAtomicAdd(hp, t0);                        // m = 0
        cp *= Ap; cn *= An;
        unsafeAtomicAdd(hp + 1, cp * E1f);
        unsafeAtomicAdd(hp - 1, cn * E1f);
        cp *= Ap; cn *= An;
        unsafeAtomicAdd(hp + 2, cp * E2f);
        unsafeAtomicAdd(hp - 2, cn * E2f);
        cp *= Ap; cn *= An;
        unsafeAtomicAdd(hp + 3, cp * E3f);
        unsafeAtomicAdd(hp - 3, cn * E3f);
        cp *= Ap; cn *= An;
        unsafeAtomicAdd(hp + 4, cp * E4f);
        unsafeAtomicAdd(hp - 4, cn * E4f);
        cp *= Ap; cn *= An;
        unsafeAtomicAdd(hp + 5, cp * E5f);
        unsafeAtomicAdd(hp - 5, cn * E5f);
        cp *= Ap; cn *= An;
        unsafeAtomicAdd(hp + 6, cp * E6f);
        unsafeAtomicAdd(hp - 6, cn * E6f);
        cp *= Ap; cn *= An;
        unsafeAtomicAdd(hp + 7, cp * E7f);
        unsafeAtomicAdd(hp - 7, cn * E7f);
        cp *= Ap;
        unsafeAtomicAdd(hp + 8, cp * E8f);              // m = +8 only
    }
}

// One wave per output row. Histogram replaces the 50-reg accumulator and the
// whole shuffle/LDS-matrix/colsum tail: tail = 4 LDS reads + 1 global store.
template <bool FUSED>
__global__ __launch_bounds__(256)
void rbf_mean_kernel(const float* __restrict__ pos,
                     float* __restrict__ meanout,   // !FUSED
                     const int* __restrict__ an,    // FUSED only
                     const float* __restrict__ te,
                     const float* __restrict__ pw,
                     const float* __restrict__ pb,
                     float* __restrict__ out)
{
    __shared__ float h[4][4 * 97];   // [wave][replica*97 + idx]   6.2 KB

    const int w    = threadIdx.x >> 6;
    const int lane = threadIdx.x & 63;
    const int row  = blockIdx.x * 4 + w;    // 0..8191
    const int b    = row >> 9;               // N = 512
    const int i    = row & 511;

    const float* posb = pos + (size_t)b * 1536;
    float* hw = &h[w][0];

    // zero this wave's histogram block (388 floats)
#pragma unroll
    for (int t = 0; t < 7; ++t) {
        const int idx = lane + t * 64;
        if (idx < 388) hw[idx] = 0.0f;
    }
    __syncthreads();   // cheap; orders zero-init before atomics

    const int i3 = __builtin_amdgcn_readfirstlane(3 * i);   // wave-uniform
    const float pix = posb[i3 + 0];
    const float piy = posb[i3 + 1];
    const float piz = posb[i3 + 2];

    rbf_hist_core(posb, lane, pix, piy, piz, hw);
    // wave-private LDS: compiler's lgkmcnt ordering suffices before reads

    float meanv = 0.0f;
    if (lane < 50) {
        meanv = (hw[8 + lane] + hw[97 + 8 + lane] +
                 hw[194 + 8 + lane] + hw[291 + 8 + lane]) * (1.0f / 512.0f);
    }

    if constexpr (!FUSED) {
        if (lane < 50) meanout[(size_t)row * 50 + lane] = meanv;
    } else {
        __shared__ float ms[4][52];
        if (lane < 50) ms[w][lane] = meanv;

        const int tok = an[row];
        float4 o = reinterpret_cast<const float4*>(pb)[lane];
        const float4 t = reinterpret_cast<const float4*>(te + (size_t)tok * 256)[lane];
        o.x += t.x; o.y += t.y; o.z += t.z; o.w += t.w;
#pragma unroll
        for (int k = 0; k < 50; ++k) {
            const float mk = ms[w][k];
            const float4 w4 = reinterpret_cast<const float4*>(pw + k * 256)[lane];
            o.x = fmaf(mk, w4.x, o.x);
            o.y = fmaf(mk, w4.y, o.y);
            o.z = fmaf(mk, w4.z, o.z);
            o.w = fmaf(mk, w4.w, o.w);
        }
        reinterpret_cast<float4*>(out)[(size_t)row * 64 + lane] = o;
    }
}

// out[row][:] = te[an[row]][:] + pb[:] + mean[row][:] @ pw   (R2-exact)
__global__ __launch_bounds__(256)
void proj_kernel(const float* __restrict__ mean,
                 const int* __restrict__ an,
                 const float* __restrict__ te,
                 const float* __restrict__ pw,
                 const float* __restrict__ pb,
                 float* __restrict__ out)
{
    const int w    = threadIdx.x >> 6;
    const int lane = threadIdx.x & 63;
    int wid = blockIdx.x * 4 + w;                       // 0..2047
    wid = __builtin_amdgcn_readfirstlane(wid);          // force SGPR
    const int row0 = wid * 4;

    const float4 bias = reinterpret_cast<const float4*>(pb)[lane];
    float4 o[4];
#pragma unroll
    for (int r = 0; r < 4; ++r) {
        const int tok = an[row0 + r];                   // wave-uniform
        const float4 t = reinterpret_cast<const float4*>(te + (size_t)tok * 256)[lane];
        o[r].x = bias.x + t.x; o[r].y = bias.y + t.y;
        o[r].z = bias.z + t.z; o[r].w = bias.w + t.w;
    }
#pragma unroll
    for (int k = 0; k < 50; ++k) {
        const float4 w4 = reinterpret_cast<const float4*>(pw + (size_t)k * 256)[lane];
#pragma unroll
        for (int r = 0; r < 4; ++r) {
            const float mk = mean[(size_t)(row0 + r) * 50 + k];  // wave-uniform
            o[r].x = fmaf(mk, w4.x, o[r].x);
            o[r].y = fmaf(mk, w4.y, o[r].y);
            o[r].z = fmaf(mk, w4.z, o[r].z);
            o[r].w = fmaf(mk, w4.w, o[r].w);
        }
    }
#pragma unroll
    for (int r = 0; r < 4; ++r)
        reinterpret_cast<float4*>(out)[(size_t)(row0 + r) * 64 + lane] = o[r];
}

extern "C" void kernel_launch(void* const* d_in, const int* in_sizes, int n_in,
                              void* d_out, int out_size, void* d_ws, size_t ws_size,
                              hipStream_t stream)
{
    const int*   an  = (const int*)  d_in[0];   // [16,512] int32
    const float* pos = (const float*)d_in[1];   // [16,512,3]
    const float* te  = (const float*)d_in[2];   // [100,256]
    const float* pw  = (const float*)d_in[3];   // [50,256]
    const float* pb  = (const float*)d_in[4];   // [256]
    float* out = (float*)d_out;                  // [16,512,256]

    const size_t mean_bytes = (size_t)8192 * 50 * sizeof(float);
    if (ws_size >= mean_bytes) {
        float* mean = (float*)d_ws;
        rbf_mean_kernel<false><<<2048, 256, 0, stream>>>(pos, mean, nullptr, nullptr,
                                                         nullptr, nullptr, nullptr);
        proj_kernel<<<512, 256, 0, stream>>>(mean, an, te, pw, pb, out);
    } else {
        rbf_mean_kernel<true><<<2048, 256, 0, stream>>>(pos, nullptr, an, te, pw, pb, out);
    }
}